// Round 2
// baseline (743.182 us; speedup 1.0000x reference)
//
#include <hip/hip_runtime.h>

#define N1 16384
#define N2 4096
#define CC 128
#define KIN 384
#define HID 256

typedef unsigned short u16;
typedef unsigned int u32;

typedef _Float16 v8h __attribute__((ext_vector_type(8)));
typedef float v4f __attribute__((ext_vector_type(4)));

// ---------- workspace layout (bytes) ----------
// W0h  fp16 256x384           @ 0        (196608)
// W1h  fp16 256x256           @ 196608   (131072)
// sst  fp32 s0,t0,s1,t1 x256  @ 327680   (4096)
// S    sorted uint4 B*N2      @ 331776   (262144)
// idx3 int B*N1*3             @ 593920   (786432)
// w3   fp32 B*N1*3            @ 1380352  (786432)
// p2t  fp32 B*N2*C            @ 2166784  (8388608)
// total = 10555392 (unchanged)

__device__ __forceinline__ u16 f2h(float f) {
    _Float16 h = (_Float16)f;
    return __builtin_bit_cast(u16, h);
}

// =====================================================================
// Prep: convert weights to fp16, fold BN into scale/shift
// =====================================================================
__global__ __launch_bounds__(256) void prep_kernel(
    const float* __restrict__ w0, const float* __restrict__ w1,
    const float* __restrict__ b0, const float* __restrict__ g0, const float* __restrict__ be0,
    const float* __restrict__ m0, const float* __restrict__ v0,
    const float* __restrict__ b1, const float* __restrict__ g1, const float* __restrict__ be1,
    const float* __restrict__ m1, const float* __restrict__ v1,
    u16* __restrict__ W0h, u16* __restrict__ W1h,
    float* __restrict__ sst)
{
    int id = blockIdx.x * 256 + threadIdx.x;
    if (id < 98304) {
        W0h[id] = f2h(w0[id]);
    } else if (id < 163840) {
        int t = id - 98304;
        W1h[t] = f2h(w1[t]);
    } else if (id < 164352) {
        int t = id - 163840;
        int o = t & 255;
        if (t < 256) {
            float s = g0[o] * rsqrtf(v0[o] + 1e-5f);
            sst[o]       = s;
            sst[256 + o] = (b0[o] - m0[o]) * s + be0[o];
        } else {
            float s = g1[o] * rsqrtf(v1[o] + 1e-5f);
            sst[512 + o] = s;
            sst[768 + o] = (b1[o] - m1[o]) * s + be1[o];
        }
    }
}

// =====================================================================
// Sort candidates of each batch by x (bitonic, one block per batch).
// S[b][i] = uint4{ bits(x), bits(y), bits(z), orig_idx }, x ascending.
// =====================================================================
__global__ __launch_bounds__(1024) void sort_kernel(
    const float* __restrict__ xyz2, uint4* __restrict__ S)
{
    __shared__ float sx[4096];   // 16 KB
    __shared__ u16   si[4096];   //  8 KB
    int b   = blockIdx.x;
    int tid = threadIdx.x;

    for (int i = tid; i < 4096; i += 1024) {
        sx[i] = xyz2[((size_t)b * 4096 + i) * 3];
        si[i] = (u16)i;
    }

    for (int k = 2; k <= 4096; k <<= 1) {
        for (int j = k >> 1; j > 0; j >>= 1) {
            __syncthreads();
            for (int t = tid; t < 4096; t += 1024) {
                int ixj = t ^ j;
                if (ixj > t) {
                    float a = sx[t], c = sx[ixj];
                    bool up = ((t & k) == 0);
                    if (up ? (a > c) : (a < c)) {
                        sx[t] = c; sx[ixj] = a;
                        u16 tmp = si[t]; si[t] = si[ixj]; si[ixj] = tmp;
                    }
                }
            }
        }
    }
    __syncthreads();

    for (int i = tid; i < 4096; i += 1024) {
        int sidx = si[i];
        size_t base = ((size_t)b * 4096 + sidx) * 3;
        uint4 o;
        o.x = __builtin_bit_cast(u32, sx[i]);
        o.y = __builtin_bit_cast(u32, xyz2[base + 1]);
        o.z = __builtin_bit_cast(u32, xyz2[base + 2]);
        o.w = (u32)sidx;
        S[(size_t)b * 4096 + i] = o;
    }
}

// =====================================================================
// Transpose points2 (B,C,N2) -> p2t (B,N2,C)  (unchanged)
// =====================================================================
__global__ __launch_bounds__(256) void transpose_kernel(
    const float* __restrict__ points2, float* __restrict__ p2t)
{
    __shared__ float tile[64][129];   // 33024 B
    int n20 = blockIdx.x * 64;
    int b   = blockIdx.y;
    int tid = threadIdx.x;

    int jr = tid & 63, cr = tid >> 6;
#pragma unroll 8
    for (int it = 0; it < 32; ++it) {
        int ch = it * 4 + cr;
        tile[jr][ch] = points2[((size_t)b * CC + ch) * N2 + n20 + jr];
    }
    __syncthreads();

    int cw = tid & 127, jw0 = tid >> 7;
#pragma unroll 8
    for (int it = 0; it < 32; ++it) {
        int j = it * 2 + jw0;
        p2t[((size_t)b * N2 + n20 + j) * CC + cw] = tile[j][cw];
    }
}

// =====================================================================
// 3-NN via x-sorted outward two-pointer scan.
// 2 lanes per query: even lane scans right from lower_bound(qx), odd lane
// scans left; each keeps a lex-correct local top-3, merged via shfl_xor(1).
//
// Correctness invariants (fixes of last round's failure):
//  * distance is the t-form t = -2 q.c + |c|^2 with |c|^2 = fmaf(x,x,
//    fmaf(y,y,z*z)) -- bit-identical selection to the proven full-scan
//    kernel (same formula, lex-on-tie == ascending-scan strict-<).
//  * no candidate is ever processed twice: out-of-range slots are MASKED
//    (t := 3e38, never inserted), not clamped -- the previous clamp
//    created duplicate inserts (INS3LEX re-insert is NOT idempotent).
//  * prune in t-space with margin: stop side when dxn^2 - pp > da2 + 1e-3.
//    Exact in real arithmetic (t = d - pp >= dx^2 - pp); the 1e-3 absolute
//    margin dominates worst-case fmaf rounding (~1e-4) for N(0,1) data.
// =====================================================================
#define BINS(t, cand, D0, D1, D2, I0, I1, I2) do {                    \
    bool c0 = (t) < (D0);                                             \
    bool c1 = (t) < (D1);                                             \
    bool c2 = (t) < (D2);                                             \
    I2 = c1 ? (I1) : (c2 ? (cand) : (I2));   /* old I1 */             \
    I1 = c0 ? (I0) : (c1 ? (cand) : (I1));   /* old I0 */             \
    I0 = c0 ? (cand) : (I0);                                          \
    D2 = __builtin_amdgcn_fmed3f((D1), (t), (D2));  /* old D1 */      \
    D1 = __builtin_amdgcn_fmed3f((D0), (t), (D1));  /* old D0 */      \
    D0 = fminf((t), (D0));                                            \
} while (0)

#define INS3LEX(t, j, D0, D1, D2, I0, I1, I2) do {                    \
    bool lt2 = (t) < (D2) || ((t) == (D2) && (j) < (I2));             \
    bool lt1 = (t) < (D1) || ((t) == (D1) && (j) < (I1));             \
    bool lt0 = (t) < (D0) || ((t) == (D0) && (j) < (I0));             \
    if (lt2) {                                                        \
        if (lt1) {                                                    \
            D2 = (D1); I2 = (I1);                                     \
            if (lt0) { D1 = (D0); I1 = (I0); D0 = (t); I0 = (j); }    \
            else     { D1 = (t); I1 = (j); }                          \
        } else { D2 = (t); I2 = (j); }                                \
    }                                                                 \
} while (0)

#define MERGE_STEP(st, D0, D1, D2, I0, I1, I2) do {                   \
    float e0 = __shfl_xor((D0), (st), 64);                            \
    float e1 = __shfl_xor((D1), (st), 64);                            \
    float e2 = __shfl_xor((D2), (st), 64);                            \
    int   j0 = __shfl_xor((I0), (st), 64);                            \
    int   j1 = __shfl_xor((I1), (st), 64);                            \
    int   j2 = __shfl_xor((I2), (st), 64);                            \
    INS3LEX(e0, j0, D0, D1, D2, I0, I1, I2);                          \
    INS3LEX(e1, j1, D0, D1, D2, I0, I1, I2);                          \
    INS3LEX(e2, j2, D0, D1, D2, I0, I1, I2);                          \
} while (0)

// process one candidate (x,y,z, idx-bits); invalid slots masked to +huge
#define PROC(c, vld) do {                                             \
    float cc_ = fmaf((c).x, (c).x, fmaf((c).y, (c).y, (c).z * (c).z));\
    float t_  = fmaf(ax, (c).x, fmaf(ay, (c).y, fmaf(az, (c).z, cc_)));\
    if (!(vld)) t_ = 3e38f;                                           \
    int  ci_ = __builtin_bit_cast(int, (c).w);                        \
    bool eq_ = (t_ == da0) || (t_ == da1) || (t_ == da2);             \
    if (__any(eq_)) { INS3LEX(t_, ci_, da0, da1, da2, ia0, ia1, ia2); }\
    else            { BINS(t_, ci_, da0, da1, da2, ia0, ia1, ia2); }  \
} while (0)

__global__ __launch_bounds__(256)
void knn_kernel(
    const float* __restrict__ xyz1, const uint4* __restrict__ S,
    int* __restrict__ idx3, float* __restrict__ w3)
{
    __shared__ __align__(16) float4 sc[4096];   // 65536 B -> 2 blocks/CU

    int tid  = threadIdx.x;
    int b    = blockIdx.y;
    int qloc = tid >> 1;
    int side = tid & 1;             // 0: scan right (x >= qx), 1: scan left
    int n    = blockIdx.x * 128 + qloc;

    // stage sorted table to LDS (coalesced)
    const uint4* Sb = S + (size_t)b * 4096;
#pragma unroll
    for (int i = 0; i < 16; ++i)
        *(uint4*)&sc[tid + i * 256] = Sb[tid + i * 256];

    size_t pb = ((size_t)b * N1 + n) * 3;
    float qx = xyz1[pb], qy = xyz1[pb + 1], qz = xyz1[pb + 2];
    float ax = -2.f * qx, ay = -2.f * qy, az = -2.f * qz;
    float pp = fmaf(qx, qx, fmaf(qy, qy, qz * qz));
    __syncthreads();

    // lower_bound: first index with x >= qx
    int lo = 0, hi = 4096;
    while (lo < hi) {
        int mid = (lo + hi) >> 1;
        if (sc[mid].x < qx) lo = mid + 1; else hi = mid;
    }
    // partition: [lo,4095] has x >= qx (R side), [0,lo-1] has x < qx (L side)

    float da0 = 1e30f, da1 = 1e30f, da2 = 1e30f;
    int   ia0 = 0, ia1 = 0, ia2 = 0;

    int  dstep = side ? -4 : 4;
    int  ptr   = side ? lo - 4 : lo;
    bool act   = side ? (ptr + 3 >= 0) : (ptr <= 4095);

    while (__any(act)) {
        if (act) {
            int i0 = ptr, i1 = ptr + 1, i2 = ptr + 2, i3 = ptr + 3;
            float4 c0 = sc[i0 & 4095];
            float4 c1 = sc[i1 & 4095];
            float4 c2 = sc[i2 & 4095];
            float4 c3 = sc[i3 & 4095];
            bool v0 = (u32)i0 < 4096u;
            bool v1 = (u32)i1 < 4096u;
            bool v2 = (u32)i2 < 4096u;
            bool v3 = (u32)i3 < 4096u;
            PROC(c0, v0); PROC(c1, v1); PROC(c2, v2); PROC(c3, v3);
            // nearest-x element of this chunk: R -> c0 (valid when act),
            // L -> c3 (valid when act). All remaining are farther in |dx|.
            float dxn = side ? (qx - c3.x) : (c0.x - qx);
            act = !(fmaf(dxn, dxn, -pp) > da2 + 1e-3f);
            ptr += dstep;
            act = act && (side ? (ptr + 3 >= 0) : (ptr <= 4095));
        }
    }

    // merge the two sides (lex tie-break) and emit
    MERGE_STEP(1, da0, da1, da2, ia0, ia1, ia2);
    if (side == 0) {
        float r0 = 1.f / (da0 + pp);
        float r1 = 1.f / (da1 + pp);
        float r2 = 1.f / (da2 + pp);
        float inv = 1.f / (r0 + r1 + r2);
        size_t o3 = ((size_t)b * N1 + n) * 3;
        idx3[o3]     = ia0;
        idx3[o3 + 1] = ia1;
        idx3[o3 + 2] = ia2;
        w3[o3]     = r0 * inv;
        w3[o3 + 1] = r1 * inv;
        w3[o3 + 2] = r2 * inv;
    }
}

// =====================================================================
// Fused interpolate + concat + MLP(384->256->256, BN+ReLU) + channel max
// (unchanged)
// =====================================================================
__global__ __launch_bounds__(256)
__attribute__((amdgpu_waves_per_eu(5, 5)))
void mlp_kernel(
    const float* __restrict__ points1, const float* __restrict__ pointsb1,
    const float4* __restrict__ p2t4,
    const int* __restrict__ idx3, const float* __restrict__ w3,
    const uint4* __restrict__ W0v, const uint4* __restrict__ W1v,
    const float* __restrict__ sst, float* __restrict__ out)
{
    __shared__ __align__(16) u16 sx[32 * KIN];   // 24576 B
    __shared__ float sred[4][32];
    __shared__ int   s_idx[96];
    __shared__ float s_w[96];

    int tid = threadIdx.x;
    int b   = blockIdx.y;
    int n0  = blockIdx.x * 32;

    if (tid < 96) {
        size_t gi = ((size_t)b * N1 + n0) * 3 + tid;
        s_idx[tid] = idx3[gi];
        s_w[tid]   = w3[gi];
    }

    int pL = tid & 31;
    int t4 = (tid >> 5) * 4;
#pragma unroll
    for (int k = 0; k < 4; ++k) {
        int r4 = t4 + 32 * k;
        size_t base = ((size_t)b * CC + r4) * N1 + n0 + pL;
        float a0 = points1[base];
        float a1 = points1[base + (size_t)N1];
        float a2 = points1[base + (size_t)2 * N1];
        float a3 = points1[base + (size_t)3 * N1];
        u32 lo = f2h(a0) | ((u32)f2h(a1) << 16);
        u32 hi = f2h(a2) | ((u32)f2h(a3) << 16);
        int chunk = (r4 >> 3) ^ (pL & 7);
        *(uint2*)&sx[pL * KIN + chunk * 8 + (r4 & 7)] = make_uint2(lo, hi);
    }
#pragma unroll
    for (int k = 0; k < 4; ++k) {
        int r4 = t4 + 32 * k;
        int k4 = 256 + r4;
        size_t base = ((size_t)b * CC + r4) * N1 + n0 + pL;
        float a0 = pointsb1[base];
        float a1 = pointsb1[base + (size_t)N1];
        float a2 = pointsb1[base + (size_t)2 * N1];
        float a3 = pointsb1[base + (size_t)3 * N1];
        u32 lo = f2h(a0) | ((u32)f2h(a1) << 16);
        u32 hi = f2h(a2) | ((u32)f2h(a3) << 16);
        int chunk = (k4 >> 3) ^ (pL & 7);
        *(uint2*)&sx[pL * KIN + chunk * 8 + (k4 & 7)] = make_uint2(lo, hi);
    }
    __syncthreads();

    int c4  = tid & 31;
    int pg  = tid >> 5;
    int k4g = 128 + c4 * 4;
#pragma unroll
    for (int k = 0; k < 4; ++k) {
        int p = pg + 8 * k;
        float w0w = s_w[p * 3 + 0], w1w = s_w[p * 3 + 1], w2w = s_w[p * 3 + 2];
        float4 f0 = p2t4[((size_t)b * N2 + s_idx[p * 3 + 0]) * 32 + c4];
        float4 f1 = p2t4[((size_t)b * N2 + s_idx[p * 3 + 1]) * 32 + c4];
        float4 f2 = p2t4[((size_t)b * N2 + s_idx[p * 3 + 2]) * 32 + c4];
        float e0 = fmaf(w0w, f0.x, fmaf(w1w, f1.x, w2w * f2.x));
        float e1 = fmaf(w0w, f0.y, fmaf(w1w, f1.y, w2w * f2.y));
        float e2 = fmaf(w0w, f0.z, fmaf(w1w, f1.z, w2w * f2.z));
        float e3 = fmaf(w0w, f0.w, fmaf(w1w, f1.w, w2w * f2.w));
        u32 lo = f2h(e0) | ((u32)f2h(e1) << 16);
        u32 hi = f2h(e2) | ((u32)f2h(e3) << 16);
        int chunk = (k4g >> 3) ^ (p & 7);
        *(uint2*)&sx[p * KIN + chunk * 8 + (k4g & 7)] = make_uint2(lo, hi);
    }
    __syncthreads();

    int lane = tid & 63, w = tid >> 6;
    int ml = lane & 15, ql = lane >> 4;
    int px7 = ml & 7;

    v4f acc1[4][2];
#pragma unroll
    for (int ot = 0; ot < 4; ++ot)
        for (int pt = 0; pt < 2; ++pt)
            acc1[ot][pt] = (v4f){0.f, 0.f, 0.f, 0.f};

#pragma unroll
    for (int s = 0; s < 12; ++s) {
        int kc = s * 4 + ql;
        int pc = (kc ^ px7) * 8;
        v8h bf0 = __builtin_bit_cast(v8h, *(const uint4*)&sx[ml * KIN + pc]);
        v8h bf1 = __builtin_bit_cast(v8h, *(const uint4*)&sx[(16 + ml) * KIN + pc]);
#pragma unroll
        for (int ot = 0; ot < 4; ++ot) {
            int o = w * 64 + ot * 16 + ml;
            v8h af = __builtin_bit_cast(v8h, W0v[o * 48 + kc]);
            acc1[ot][0] = __builtin_amdgcn_mfma_f32_16x16x32_f16(af, bf0, acc1[ot][0], 0, 0, 0);
            acc1[ot][1] = __builtin_amdgcn_mfma_f32_16x16x32_f16(af, bf1, acc1[ot][1], 0, 0, 0);
        }
    }
    __syncthreads();

    const float* s0v = sst;
    const float* t0v = sst + 256;
#pragma unroll
    for (int ot = 0; ot < 4; ++ot) {
        int o0 = w * 64 + ot * 16 + ql * 4;
        float sc0 = s0v[o0], sc1 = s0v[o0 + 1], sc2 = s0v[o0 + 2], sc3 = s0v[o0 + 3];
        float sh0 = t0v[o0], sh1 = t0v[o0 + 1], sh2 = t0v[o0 + 2], sh3 = t0v[o0 + 3];
        int chunk = ((o0 >> 3) ^ px7);
#pragma unroll
        for (int pt = 0; pt < 2; ++pt) {
            int p = pt * 16 + ml;
            float z0 = fmaxf(fmaf(acc1[ot][pt][0], sc0, sh0), 0.f);
            float z1 = fmaxf(fmaf(acc1[ot][pt][1], sc1, sh1), 0.f);
            float z2 = fmaxf(fmaf(acc1[ot][pt][2], sc2, sh2), 0.f);
            float z3 = fmaxf(fmaf(acc1[ot][pt][3], sc3, sh3), 0.f);
            u32 lo = f2h(z0) | ((u32)f2h(z1) << 16);
            u32 hi = f2h(z2) | ((u32)f2h(z3) << 16);
            *(uint2*)&sx[p * HID + chunk * 8 + (o0 & 7)] = make_uint2(lo, hi);
        }
    }
    __syncthreads();

    v4f acc2[4][2];
#pragma unroll
    for (int ot = 0; ot < 4; ++ot)
        for (int pt = 0; pt < 2; ++pt)
            acc2[ot][pt] = (v4f){0.f, 0.f, 0.f, 0.f};

#pragma unroll
    for (int s = 0; s < 8; ++s) {
        int kc = s * 4 + ql;
        int pc = (kc ^ px7) * 8;
        v8h bf0 = __builtin_bit_cast(v8h, *(const uint4*)&sx[ml * HID + pc]);
        v8h bf1 = __builtin_bit_cast(v8h, *(const uint4*)&sx[(16 + ml) * HID + pc]);
#pragma unroll
        for (int ot = 0; ot < 4; ++ot) {
            int o = w * 64 + ot * 16 + ml;
            v8h af = __builtin_bit_cast(v8h, W1v[o * 32 + kc]);
            acc2[ot][0] = __builtin_amdgcn_mfma_f32_16x16x32_f16(af, bf0, acc2[ot][0], 0, 0, 0);
            acc2[ot][1] = __builtin_amdgcn_mfma_f32_16x16x32_f16(af, bf1, acc2[ot][1], 0, 0, 0);
        }
    }

    const float* s1v = sst + 512;
    const float* t1v = sst + 768;
    float mx0 = 0.f, mx1 = 0.f;
#pragma unroll
    for (int ot = 0; ot < 4; ++ot) {
        int o0 = w * 64 + ot * 16 + ql * 4;
#pragma unroll
        for (int r = 0; r < 4; ++r) {
            float sc = s1v[o0 + r], sh = t1v[o0 + r];
            mx0 = fmaxf(mx0, fmaf(acc2[ot][0][r], sc, sh));
            mx1 = fmaxf(mx1, fmaf(acc2[ot][1][r], sc, sh));
        }
    }
    mx0 = fmaxf(mx0, __shfl_xor(mx0, 16, 64));
    mx0 = fmaxf(mx0, __shfl_xor(mx0, 32, 64));
    mx1 = fmaxf(mx1, __shfl_xor(mx1, 16, 64));
    mx1 = fmaxf(mx1, __shfl_xor(mx1, 32, 64));
    if (lane < 16) {
        sred[w][ml]      = mx0;
        sred[w][16 + ml] = mx1;
    }
    __syncthreads();
    if (tid < 32)
        out[(size_t)b * N1 + n0 + tid] =
            fmaxf(fmaxf(sred[0][tid], sred[1][tid]),
                  fmaxf(sred[2][tid], sred[3][tid]));
}

// =====================================================================
extern "C" void kernel_launch(void* const* d_in, const int* in_sizes, int n_in,
                              void* d_out, int out_size, void* d_ws, size_t ws_size,
                              hipStream_t stream)
{
    const float* xyz1     = (const float*)d_in[0];
    const float* xyz2     = (const float*)d_in[1];
    const float* points2  = (const float*)d_in[2];
    const float* points1  = (const float*)d_in[3];
    const float* pointsb1 = (const float*)d_in[4];
    const float* w0   = (const float*)d_in[5];
    const float* b0   = (const float*)d_in[6];
    const float* g0   = (const float*)d_in[7];
    const float* be0  = (const float*)d_in[8];
    const float* m0   = (const float*)d_in[9];
    const float* v0   = (const float*)d_in[10];
    const float* w1   = (const float*)d_in[11];
    const float* b1   = (const float*)d_in[12];
    const float* g1   = (const float*)d_in[13];
    const float* be1  = (const float*)d_in[14];
    const float* m1   = (const float*)d_in[15];
    const float* v1   = (const float*)d_in[16];
    float* out = (float*)d_out;

    char* ws = (char*)d_ws;
    u16*    W0h   = (u16*)(ws + 0);
    u16*    W1h   = (u16*)(ws + 196608);
    float*  sst   = (float*)(ws + 327680);
    uint4*  S     = (uint4*)(ws + 331776);
    int*    idx3  = (int*)(ws + 593920);
    float*  w3    = (float*)(ws + 1380352);
    float*  p2t   = (float*)(ws + 2166784);

    prep_kernel<<<642, 256, 0, stream>>>(w0, w1, b0, g0, be0, m0, v0,
                                         b1, g1, be1, m1, v1,
                                         W0h, W1h, sst);
    sort_kernel<<<4, 1024, 0, stream>>>(xyz2, S);
    transpose_kernel<<<dim3(64, 4), 256, 0, stream>>>(points2, p2t);
    knn_kernel<<<dim3(128, 4), 256, 0, stream>>>(xyz1, S, idx3, w3);
    mlp_kernel<<<dim3(512, 4), 256, 0, stream>>>(points1, pointsb1,
                                                 (const float4*)p2t, idx3, w3,
                                                 (const uint4*)W0h, (const uint4*)W1h,
                                                 sst, out);
}

// Round 4
// 316.912 us; speedup vs baseline: 2.3451x; 2.3451x over previous
//
#include <hip/hip_runtime.h>

#define N1 16384
#define N2 4096
#define CC 128
#define KIN 384
#define HID 256

typedef unsigned short u16;
typedef unsigned int u32;

typedef _Float16 v8h __attribute__((ext_vector_type(8)));
typedef float v4f __attribute__((ext_vector_type(4)));

// ---------- workspace layout (bytes) ----------
// W0h  fp16 256x384           @ 0        (196608)
// W1h  fp16 256x256           @ 196608   (131072)
// sst  fp32 s0,t0,s1,t1 x256  @ 327680   (4096)
// xyz2q float4 B*N2           @ 331776   (262144)
// idx3 int B*N1*3             @ 593920   (786432)
// w3   fp32 B*N1*3            @ 1380352  (786432)
// p2t  fp32 B*N2*C            @ 2166784  (8388608)
// total = 10555392

__device__ __forceinline__ u16 f2h(float f) {
    _Float16 h = (_Float16)f;
    return __builtin_bit_cast(u16, h);
}

// =====================================================================
// Fused prep + transpose (independent stages, one dispatch).
// Blocks [0,256): transpose points2 (B,C,N2) -> p2t (B,N2,C)
//   (128ch x 64n2 tile, LDS pad +1: 2-way = free)
// Blocks [256,962): weights->fp16, fold BN into scale/shift, xyz2q
// Bodies are byte-identical to the proven split kernels; only the
// block-index remap differs (n20=(bid&63)*64, b=bid>>6; id offset -256).
// =====================================================================
__global__ __launch_bounds__(256) void prep_transpose_kernel(
    const float* __restrict__ w0, const float* __restrict__ w1,
    const float* __restrict__ b0, const float* __restrict__ g0, const float* __restrict__ be0,
    const float* __restrict__ m0, const float* __restrict__ v0,
    const float* __restrict__ b1, const float* __restrict__ g1, const float* __restrict__ be1,
    const float* __restrict__ m1, const float* __restrict__ v1,
    const float* __restrict__ xyz2, const float* __restrict__ points2,
    u16* __restrict__ W0h, u16* __restrict__ W1h,
    float* __restrict__ sst, float4* __restrict__ xyz2q,
    float* __restrict__ p2t)
{
    __shared__ float tile[64][129];   // 33024 B (transpose blocks only)
    int tid = threadIdx.x;

    if (blockIdx.x < 256) {
        // ---------------- transpose ----------------
        int bid = blockIdx.x;
        int n20 = (bid & 63) * 64;
        int b   = bid >> 6;

        int jr = tid & 63, cr = tid >> 6;        // read: 4 ch x 64 n2 per iter
#pragma unroll 8
        for (int it = 0; it < 32; ++it) {
            int ch = it * 4 + cr;
            tile[jr][ch] = points2[((size_t)b * CC + ch) * N2 + n20 + jr];
        }
        __syncthreads();

        int cw = tid & 127, jw0 = tid >> 7;      // write: 2 rows x 128 ch per iter
#pragma unroll 8
        for (int it = 0; it < 32; ++it) {
            int j = it * 2 + jw0;
            p2t[((size_t)b * N2 + n20 + j) * CC + cw] = tile[j][cw];
        }
        return;
    }

    // ---------------- prep ----------------
    int id = (blockIdx.x - 256) * 256 + tid;
    if (id < 98304) {
        W0h[id] = f2h(w0[id]);
    } else if (id < 163840) {
        int t = id - 98304;
        W1h[t] = f2h(w1[t]);
    } else if (id < 164352) {
        int t = id - 163840;
        int o = t & 255;
        if (t < 256) {
            float s = g0[o] * rsqrtf(v0[o] + 1e-5f);
            sst[o]       = s;
            sst[256 + o] = (b0[o] - m0[o]) * s + be0[o];
        } else {
            float s = g1[o] * rsqrtf(v1[o] + 1e-5f);
            sst[512 + o] = s;
            sst[768 + o] = (b1[o] - m1[o]) * s + be1[o];
        }
    } else if (id < 180736) {
        int t = id - 164352;  // b*N2+n
        float x = xyz2[(size_t)t * 3 + 0];
        float y = xyz2[(size_t)t * 3 + 1];
        float z = xyz2[(size_t)t * 3 + 2];
        xyz2q[t] = make_float4(x, y, z, fmaf(x, x, fmaf(y, y, z * z)));
    }
}

// =====================================================================
// 3-NN + inverse-distance weights (PROVEN 122us kernel, verbatim)
// 256 thr / block, 32 queries / block, 2 queries / thread (named scalars),
// 16-way candidate split; candidates staged in 4 stages x 1024 float4
// (16 KB LDS). Grid 2048 = 8 blocks/CU, waves_per_eu(8,8) -> 8 waves/SIMD.
// Dense 16-split brute is instruction-optimal (~0.057 wave-instr/pair);
// windowed scans lose to wave-divergence + gating granularity (R2/R3).
// =====================================================================
#define BINS(t, cand, D0, D1, D2, I0, I1, I2) do {                    \
    bool c0 = (t) < (D0);                                             \
    bool c1 = (t) < (D1);                                             \
    bool c2 = (t) < (D2);                                             \
    I2 = c1 ? (I1) : (c2 ? (cand) : (I2));   /* old I1 */             \
    I1 = c0 ? (I0) : (c1 ? (cand) : (I1));   /* old I0 */             \
    I0 = c0 ? (cand) : (I0);                                          \
    D2 = __builtin_amdgcn_fmed3f((D1), (t), (D2));  /* old D1 */      \
    D1 = __builtin_amdgcn_fmed3f((D0), (t), (D1));  /* old D0 */      \
    D0 = fminf((t), (D0));                                            \
} while (0)

#define INS3LEX(t, j, D0, D1, D2, I0, I1, I2) do {                    \
    bool lt2 = (t) < (D2) || ((t) == (D2) && (j) < (I2));             \
    bool lt1 = (t) < (D1) || ((t) == (D1) && (j) < (I1));             \
    bool lt0 = (t) < (D0) || ((t) == (D0) && (j) < (I0));             \
    if (lt2) {                                                        \
        if (lt1) {                                                    \
            D2 = (D1); I2 = (I1);                                     \
            if (lt0) { D1 = (D0); I1 = (I0); D0 = (t); I0 = (j); }    \
            else     { D1 = (t); I1 = (j); }                          \
        } else { D2 = (t); I2 = (j); }                                \
    }                                                                 \
} while (0)

#define MERGE_STEP(st, D0, D1, D2, I0, I1, I2) do {                   \
    float e0 = __shfl_xor((D0), (st), 64);                            \
    float e1 = __shfl_xor((D1), (st), 64);                            \
    float e2 = __shfl_xor((D2), (st), 64);                            \
    int   j0 = __shfl_xor((I0), (st), 64);                            \
    int   j1 = __shfl_xor((I1), (st), 64);                            \
    int   j2 = __shfl_xor((I2), (st), 64);                            \
    INS3LEX(e0, j0, D0, D1, D2, I0, I1, I2);                          \
    INS3LEX(e1, j1, D0, D1, D2, I0, I1, I2);                          \
    INS3LEX(e2, j2, D0, D1, D2, I0, I1, I2);                          \
} while (0)

#define KNN_OUT(Q, D0, D1, D2, I0, I1, I2, PP) do {                   \
    float r0 = 1.f / ((D0) + (PP));                                   \
    float r1 = 1.f / ((D1) + (PP));                                   \
    float r2 = 1.f / ((D2) + (PP));                                   \
    float inv = 1.f / (r0 + r1 + r2);                                 \
    size_t o3 = ((size_t)b * N1 + p0 + (Q)) * 3;                      \
    idx3[o3]     = (I0);                                              \
    idx3[o3 + 1] = (I1);                                              \
    idx3[o3 + 2] = (I2);                                              \
    w3[o3]     = r0 * inv;                                            \
    w3[o3 + 1] = r1 * inv;                                            \
    w3[o3 + 2] = r2 * inv;                                            \
} while (0)

__global__ __launch_bounds__(256)
__attribute__((amdgpu_waves_per_eu(8, 8)))
void knn_kernel(
    const float* __restrict__ xyz1, const float4* __restrict__ xyz2q,
    int* __restrict__ idx3, float* __restrict__ w3)
{
    __shared__ float4 slds[1024];   // 16384 B

    int tid = threadIdx.x;
    int b   = blockIdx.y;
    int n0  = blockIdx.x * 32;

    int s  = tid & 15;      // candidate split (lane bits 0..3)
    int g  = tid >> 4;      // query group 0..15
    int p0 = n0 + g * 2;

    size_t pb = ((size_t)b * N1 + p0) * 3;
    float x0 = xyz1[pb + 0], y0 = xyz1[pb + 1], z0 = xyz1[pb + 2];
    float x1 = xyz1[pb + 3], y1 = xyz1[pb + 4], z1 = xyz1[pb + 5];
    float ax0 = -2.f * x0, ay0 = -2.f * y0, az0 = -2.f * z0;
    float ax1 = -2.f * x1, ay1 = -2.f * y1, az1 = -2.f * z1;
    float pp0 = fmaf(x0, x0, fmaf(y0, y0, z0 * z0));
    float pp1 = fmaf(x1, x1, fmaf(y1, y1, z1 * z1));

    float da0 = 1e30f, da1 = 1e30f, da2 = 1e30f;
    float db0 = 1e30f, db1 = 1e30f, db2 = 1e30f;
    int   ia0 = 0, ia1 = 0, ia2 = 0;
    int   ib0 = 0, ib1 = 0, ib2 = 0;

#pragma unroll
    for (int stage = 0; stage < 4; ++stage) {
        int base = stage * 1024;
        // stage candidates to LDS (coalesced 16B)
#pragma unroll
        for (int i = 0; i < 4; ++i)
            slds[tid + i * 256] = xyz2q[(size_t)b * N2 + base + tid + i * 256];
        __syncthreads();

        // thread s scans candidates s, s+16, ... ascending across stages ->
        // strict < keeps lowest-index-on-tie, matching stable top_k.
#pragma unroll 4
        for (int k = 0; k < 64; ++k) {
            int c = s + (k << 4);
            float4 v = slds[c];
            int cand = base + c;
            float t0 = fmaf(ax0, v.x, fmaf(ay0, v.y, fmaf(az0, v.z, v.w)));
            float t1 = fmaf(ax1, v.x, fmaf(ay1, v.y, fmaf(az1, v.z, v.w)));
            BINS(t0, cand, da0, da1, da2, ia0, ia1, ia2);
            BINS(t1, cand, db0, db1, db2, ib0, ib1, ib2);
        }
        __syncthreads();   // protect LDS overwrite by next stage
    }

    // butterfly merge across the 16 splits (lex tie-break by true index)
#pragma unroll
    for (int st = 1; st <= 8; st <<= 1) {
        MERGE_STEP(st, da0, da1, da2, ia0, ia1, ia2);
        MERGE_STEP(st, db0, db1, db2, ib0, ib1, ib2);
    }

    if (s == 0) {
        KNN_OUT(0, da0, da1, da2, ia0, ia1, ia2, pp0);
        KNN_OUT(1, db0, db1, db2, ib0, ib1, ib2, pp1);
    }
}

// =====================================================================
// Fused interpolate + concat + MLP(384->256->256, BN+ReLU) + channel max
// (proven kernel, verbatim)
// =====================================================================
__global__ __launch_bounds__(256)
__attribute__((amdgpu_waves_per_eu(5, 5)))
void mlp_kernel(
    const float* __restrict__ points1, const float* __restrict__ pointsb1,
    const float4* __restrict__ p2t4,
    const int* __restrict__ idx3, const float* __restrict__ w3,
    const uint4* __restrict__ W0v, const uint4* __restrict__ W1v,
    const float* __restrict__ sst, float* __restrict__ out)
{
    // x: 32 rows x 384 fp16, 16B-chunk swizzled by (p&7); h1 overlays (32x256)
    __shared__ __align__(16) u16 sx[32 * KIN];   // 24576 B
    __shared__ float sred[4][32];
    __shared__ int   s_idx[96];
    __shared__ float s_w[96];

    int tid = threadIdx.x;
    int b   = blockIdx.y;
    int n0  = blockIdx.x * 32;

    if (tid < 96) {
        size_t gi = ((size_t)b * N1 + n0) * 3 + tid;
        s_idx[tid] = idx3[gi];
        s_w[tid]   = w3[gi];
    }

    // ---- stage x rows 0..127 (points1) + 256..383 (points_b1) ----
    int pL = tid & 31;
    int t4 = (tid >> 5) * 4;          // 0,4,...,28
#pragma unroll
    for (int k = 0; k < 4; ++k) {
        int r4 = t4 + 32 * k;
        size_t base = ((size_t)b * CC + r4) * N1 + n0 + pL;
        float a0 = points1[base];
        float a1 = points1[base + (size_t)N1];
        float a2 = points1[base + (size_t)2 * N1];
        float a3 = points1[base + (size_t)3 * N1];
        u32 lo = f2h(a0) | ((u32)f2h(a1) << 16);
        u32 hi = f2h(a2) | ((u32)f2h(a3) << 16);
        int chunk = (r4 >> 3) ^ (pL & 7);
        *(uint2*)&sx[pL * KIN + chunk * 8 + (r4 & 7)] = make_uint2(lo, hi);
    }
#pragma unroll
    for (int k = 0; k < 4; ++k) {
        int r4 = t4 + 32 * k;
        int k4 = 256 + r4;
        size_t base = ((size_t)b * CC + r4) * N1 + n0 + pL;
        float a0 = pointsb1[base];
        float a1 = pointsb1[base + (size_t)N1];
        float a2 = pointsb1[base + (size_t)2 * N1];
        float a3 = pointsb1[base + (size_t)3 * N1];
        u32 lo = f2h(a0) | ((u32)f2h(a1) << 16);
        u32 hi = f2h(a2) | ((u32)f2h(a3) << 16);
        int chunk = (k4 >> 3) ^ (pL & 7);
        *(uint2*)&sx[pL * KIN + chunk * 8 + (k4 & 7)] = make_uint2(lo, hi);
    }
    __syncthreads();   // s_idx/s_w visible for gather

    // ---- stage x rows 128..255: 3-NN interpolation from p2t rows ----
    int c4  = tid & 31;
    int pg  = tid >> 5;
    int k4g = 128 + c4 * 4;
#pragma unroll
    for (int k = 0; k < 4; ++k) {
        int p = pg + 8 * k;
        float w0w = s_w[p * 3 + 0], w1w = s_w[p * 3 + 1], w2w = s_w[p * 3 + 2];
        float4 f0 = p2t4[((size_t)b * N2 + s_idx[p * 3 + 0]) * 32 + c4];
        float4 f1 = p2t4[((size_t)b * N2 + s_idx[p * 3 + 1]) * 32 + c4];
        float4 f2 = p2t4[((size_t)b * N2 + s_idx[p * 3 + 2]) * 32 + c4];
        float e0 = fmaf(w0w, f0.x, fmaf(w1w, f1.x, w2w * f2.x));
        float e1 = fmaf(w0w, f0.y, fmaf(w1w, f1.y, w2w * f2.y));
        float e2 = fmaf(w0w, f0.z, fmaf(w1w, f1.z, w2w * f2.z));
        float e3 = fmaf(w0w, f0.w, fmaf(w1w, f1.w, w2w * f2.w));
        u32 lo = f2h(e0) | ((u32)f2h(e1) << 16);
        u32 hi = f2h(e2) | ((u32)f2h(e3) << 16);
        int chunk = (k4g >> 3) ^ (p & 7);
        *(uint2*)&sx[p * KIN + chunk * 8 + (k4g & 7)] = make_uint2(lo, hi);
    }
    __syncthreads();

    int lane = tid & 63, w = tid >> 6;      // wave w: o in [w*64, w*64+64)
    int ml = lane & 15, ql = lane >> 4;     // frag row/col, quad
    int px7 = ml & 7;                       // == p&7 for both pt (p=pt*16+ml)

    // ---------------- GEMM1: h1 = W0 @ x ----------------
    v4f acc1[4][2];
#pragma unroll
    for (int ot = 0; ot < 4; ++ot)
        for (int pt = 0; pt < 2; ++pt)
            acc1[ot][pt] = (v4f){0.f, 0.f, 0.f, 0.f};

#pragma unroll
    for (int s = 0; s < 12; ++s) {
        int kc = s * 4 + ql;
        int pc = (kc ^ px7) * 8;
        v8h bf0 = __builtin_bit_cast(v8h, *(const uint4*)&sx[ml * KIN + pc]);
        v8h bf1 = __builtin_bit_cast(v8h, *(const uint4*)&sx[(16 + ml) * KIN + pc]);
#pragma unroll
        for (int ot = 0; ot < 4; ++ot) {
            int o = w * 64 + ot * 16 + ml;
            v8h af = __builtin_bit_cast(v8h, W0v[o * 48 + kc]);
            acc1[ot][0] = __builtin_amdgcn_mfma_f32_16x16x32_f16(af, bf0, acc1[ot][0], 0, 0, 0);
            acc1[ot][1] = __builtin_amdgcn_mfma_f32_16x16x32_f16(af, bf1, acc1[ot][1], 0, 0, 0);
        }
    }
    __syncthreads();   // all x reads done before h1 overlays sx

    // epilogue 1: BN+ReLU -> fp16 h1[p][o] (row stride 256, swizzled)
    const float* s0v = sst;
    const float* t0v = sst + 256;
#pragma unroll
    for (int ot = 0; ot < 4; ++ot) {
        int o0 = w * 64 + ot * 16 + ql * 4;
        float sc0 = s0v[o0], sc1 = s0v[o0 + 1], sc2 = s0v[o0 + 2], sc3 = s0v[o0 + 3];
        float sh0 = t0v[o0], sh1 = t0v[o0 + 1], sh2 = t0v[o0 + 2], sh3 = t0v[o0 + 3];
        int chunk = ((o0 >> 3) ^ px7);
#pragma unroll
        for (int pt = 0; pt < 2; ++pt) {
            int p = pt * 16 + ml;
            float z0 = fmaxf(fmaf(acc1[ot][pt][0], sc0, sh0), 0.f);
            float z1 = fmaxf(fmaf(acc1[ot][pt][1], sc1, sh1), 0.f);
            float z2 = fmaxf(fmaf(acc1[ot][pt][2], sc2, sh2), 0.f);
            float z3 = fmaxf(fmaf(acc1[ot][pt][3], sc3, sh3), 0.f);
            u32 lo = f2h(z0) | ((u32)f2h(z1) << 16);
            u32 hi = f2h(z2) | ((u32)f2h(z3) << 16);
            *(uint2*)&sx[p * HID + chunk * 8 + (o0 & 7)] = make_uint2(lo, hi);
        }
    }
    __syncthreads();

    // ---------------- GEMM2: h2 = W1 @ h1 ----------------
    v4f acc2[4][2];
#pragma unroll
    for (int ot = 0; ot < 4; ++ot)
        for (int pt = 0; pt < 2; ++pt)
            acc2[ot][pt] = (v4f){0.f, 0.f, 0.f, 0.f};

#pragma unroll
    for (int s = 0; s < 8; ++s) {
        int kc = s * 4 + ql;
        int pc = (kc ^ px7) * 8;
        v8h bf0 = __builtin_bit_cast(v8h, *(const uint4*)&sx[ml * HID + pc]);
        v8h bf1 = __builtin_bit_cast(v8h, *(const uint4*)&sx[(16 + ml) * HID + pc]);
#pragma unroll
        for (int ot = 0; ot < 4; ++ot) {
            int o = w * 64 + ot * 16 + ml;
            v8h af = __builtin_bit_cast(v8h, W1v[o * 32 + kc]);
            acc2[ot][0] = __builtin_amdgcn_mfma_f32_16x16x32_f16(af, bf0, acc2[ot][0], 0, 0, 0);
            acc2[ot][1] = __builtin_amdgcn_mfma_f32_16x16x32_f16(af, bf1, acc2[ot][1], 0, 0, 0);
        }
    }

    // epilogue 2: BN + ReLU (via max with 0) + channel max over this wave's 64 o
    const float* s1v = sst + 512;
    const float* t1v = sst + 768;
    float mx0 = 0.f, mx1 = 0.f;   // relu floor = 0
#pragma unroll
    for (int ot = 0; ot < 4; ++ot) {
        int o0 = w * 64 + ot * 16 + ql * 4;
#pragma unroll
        for (int r = 0; r < 4; ++r) {
            float sc = s1v[o0 + r], sh = t1v[o0 + r];
            mx0 = fmaxf(mx0, fmaf(acc2[ot][0][r], sc, sh));
            mx1 = fmaxf(mx1, fmaf(acc2[ot][1][r], sc, sh));
        }
    }
    mx0 = fmaxf(mx0, __shfl_xor(mx0, 16, 64));
    mx0 = fmaxf(mx0, __shfl_xor(mx0, 32, 64));
    mx1 = fmaxf(mx1, __shfl_xor(mx1, 16, 64));
    mx1 = fmaxf(mx1, __shfl_xor(mx1, 32, 64));
    if (lane < 16) {
        sred[w][ml]      = mx0;
        sred[w][16 + ml] = mx1;
    }
    __syncthreads();
    if (tid < 32)
        out[(size_t)b * N1 + n0 + tid] =
            fmaxf(fmaxf(sred[0][tid], sred[1][tid]),
                  fmaxf(sred[2][tid], sred[3][tid]));
}

// =====================================================================
extern "C" void kernel_launch(void* const* d_in, const int* in_sizes, int n_in,
                              void* d_out, int out_size, void* d_ws, size_t ws_size,
                              hipStream_t stream)
{
    const float* xyz1     = (const float*)d_in[0];
    const float* xyz2     = (const float*)d_in[1];
    const float* points2  = (const float*)d_in[2];
    const float* points1  = (const float*)d_in[3];
    const float* pointsb1 = (const float*)d_in[4];
    const float* w0   = (const float*)d_in[5];
    const float* b0   = (const float*)d_in[6];
    const float* g0   = (const float*)d_in[7];
    const float* be0  = (const float*)d_in[8];
    const float* m0   = (const float*)d_in[9];
    const float* v0   = (const float*)d_in[10];
    const float* w1   = (const float*)d_in[11];
    const float* b1   = (const float*)d_in[12];
    const float* g1   = (const float*)d_in[13];
    const float* be1  = (const float*)d_in[14];
    const float* m1   = (const float*)d_in[15];
    const float* v1   = (const float*)d_in[16];
    float* out = (float*)d_out;

    char* ws = (char*)d_ws;
    u16*    W0h   = (u16*)(ws + 0);
    u16*    W1h   = (u16*)(ws + 196608);
    float*  sst   = (float*)(ws + 327680);
    float4* xyz2q = (float4*)(ws + 331776);
    int*    idx3  = (int*)(ws + 593920);
    float*  w3    = (float*)(ws + 1380352);
    float*  p2t   = (float*)(ws + 2166784);

    prep_transpose_kernel<<<962, 256, 0, stream>>>(
        w0, w1, b0, g0, be0, m0, v0,
        b1, g1, be1, m1, v1,
        xyz2, points2,
        W0h, W1h, sst, xyz2q, p2t);
    knn_kernel<<<dim3(512, 4), 256, 0, stream>>>(xyz1, xyz2q, idx3, w3);
    mlp_kernel<<<dim3(512, 4), 256, 0, stream>>>(points1, pointsb1,
                                                 (const float4*)p2t, idx3, w3,
                                                 (const uint4*)W0h, (const uint4*)W1h,
                                                 sst, out);
}

// Round 5
// 279.546 us; speedup vs baseline: 2.6585x; 1.1337x over previous
//
#include <hip/hip_runtime.h>

#define N1 16384
#define N2 4096
#define CC 128
#define KIN 384
#define HID 256

typedef unsigned short u16;
typedef unsigned int u32;

typedef _Float16 v8h __attribute__((ext_vector_type(8)));
typedef float v4f __attribute__((ext_vector_type(4)));

// ---------- workspace layout (bytes) ----------
// W0h  fp16 256x384           @ 0        (196608)
// W1h  fp16 256x256           @ 196608   (131072)
// sst  fp32 s0,t0,s1,t1 x256  @ 327680   (4096)
// xyz2q float4 B*N2           @ 331776   (262144)
// idx3 int B*N1*3             @ 593920   (786432)
// w3   fp32 B*N1*3            @ 1380352  (786432)
// p2t  fp32 B*N2*C            @ 2166784  (8388608)
// total = 10555392

__device__ __forceinline__ u16 f2h(float f) {
    _Float16 h = (_Float16)f;
    return __builtin_bit_cast(u16, h);
}

// =====================================================================
// Fused prep + transpose (proven, verbatim from R4-passing kernel)
// =====================================================================
__global__ __launch_bounds__(256) void prep_transpose_kernel(
    const float* __restrict__ w0, const float* __restrict__ w1,
    const float* __restrict__ b0, const float* __restrict__ g0, const float* __restrict__ be0,
    const float* __restrict__ m0, const float* __restrict__ v0,
    const float* __restrict__ b1, const float* __restrict__ g1, const float* __restrict__ be1,
    const float* __restrict__ m1, const float* __restrict__ v1,
    const float* __restrict__ xyz2, const float* __restrict__ points2,
    u16* __restrict__ W0h, u16* __restrict__ W1h,
    float* __restrict__ sst, float4* __restrict__ xyz2q,
    float* __restrict__ p2t)
{
    __shared__ float tile[64][129];   // 33024 B (transpose blocks only)
    int tid = threadIdx.x;

    if (blockIdx.x < 256) {
        int bid = blockIdx.x;
        int n20 = (bid & 63) * 64;
        int b   = bid >> 6;

        int jr = tid & 63, cr = tid >> 6;
#pragma unroll 8
        for (int it = 0; it < 32; ++it) {
            int ch = it * 4 + cr;
            tile[jr][ch] = points2[((size_t)b * CC + ch) * N2 + n20 + jr];
        }
        __syncthreads();

        int cw = tid & 127, jw0 = tid >> 7;
#pragma unroll 8
        for (int it = 0; it < 32; ++it) {
            int j = it * 2 + jw0;
            p2t[((size_t)b * N2 + n20 + j) * CC + cw] = tile[j][cw];
        }
        return;
    }

    int id = (blockIdx.x - 256) * 256 + tid;
    if (id < 98304) {
        W0h[id] = f2h(w0[id]);
    } else if (id < 163840) {
        int t = id - 98304;
        W1h[t] = f2h(w1[t]);
    } else if (id < 164352) {
        int t = id - 163840;
        int o = t & 255;
        if (t < 256) {
            float s = g0[o] * rsqrtf(v0[o] + 1e-5f);
            sst[o]       = s;
            sst[256 + o] = (b0[o] - m0[o]) * s + be0[o];
        } else {
            float s = g1[o] * rsqrtf(v1[o] + 1e-5f);
            sst[512 + o] = s;
            sst[768 + o] = (b1[o] - m1[o]) * s + be1[o];
        }
    } else if (id < 180736) {
        int t = id - 164352;  // b*N2+n
        float x = xyz2[(size_t)t * 3 + 0];
        float y = xyz2[(size_t)t * 3 + 1];
        float z = xyz2[(size_t)t * 3 + 2];
        xyz2q[t] = make_float4(x, y, z, fmaf(x, x, fmaf(y, y, z * z)));
    }
}

// =====================================================================
// 3-NN + inverse-distance weights (PROVEN 121us kernel, verbatim)
// =====================================================================
#define BINS(t, cand, D0, D1, D2, I0, I1, I2) do {                    \
    bool c0 = (t) < (D0);                                             \
    bool c1 = (t) < (D1);                                             \
    bool c2 = (t) < (D2);                                             \
    I2 = c1 ? (I1) : (c2 ? (cand) : (I2));   /* old I1 */             \
    I1 = c0 ? (I0) : (c1 ? (cand) : (I1));   /* old I0 */             \
    I0 = c0 ? (cand) : (I0);                                          \
    D2 = __builtin_amdgcn_fmed3f((D1), (t), (D2));  /* old D1 */      \
    D1 = __builtin_amdgcn_fmed3f((D0), (t), (D1));  /* old D0 */      \
    D0 = fminf((t), (D0));                                            \
} while (0)

#define INS3LEX(t, j, D0, D1, D2, I0, I1, I2) do {                    \
    bool lt2 = (t) < (D2) || ((t) == (D2) && (j) < (I2));             \
    bool lt1 = (t) < (D1) || ((t) == (D1) && (j) < (I1));             \
    bool lt0 = (t) < (D0) || ((t) == (D0) && (j) < (I0));             \
    if (lt2) {                                                        \
        if (lt1) {                                                    \
            D2 = (D1); I2 = (I1);                                     \
            if (lt0) { D1 = (D0); I1 = (I0); D0 = (t); I0 = (j); }    \
            else     { D1 = (t); I1 = (j); }                          \
        } else { D2 = (t); I2 = (j); }                                \
    }                                                                 \
} while (0)

#define MERGE_STEP(st, D0, D1, D2, I0, I1, I2) do {                   \
    float e0 = __shfl_xor((D0), (st), 64);                            \
    float e1 = __shfl_xor((D1), (st), 64);                            \
    float e2 = __shfl_xor((D2), (st), 64);                            \
    int   j0 = __shfl_xor((I0), (st), 64);                            \
    int   j1 = __shfl_xor((I1), (st), 64);                            \
    int   j2 = __shfl_xor((I2), (st), 64);                            \
    INS3LEX(e0, j0, D0, D1, D2, I0, I1, I2);                          \
    INS3LEX(e1, j1, D0, D1, D2, I0, I1, I2);                          \
    INS3LEX(e2, j2, D0, D1, D2, I0, I1, I2);                          \
} while (0)

#define KNN_OUT(Q, D0, D1, D2, I0, I1, I2, PP) do {                   \
    float r0 = 1.f / ((D0) + (PP));                                   \
    float r1 = 1.f / ((D1) + (PP));                                   \
    float r2 = 1.f / ((D2) + (PP));                                   \
    float inv = 1.f / (r0 + r1 + r2);                                 \
    size_t o3 = ((size_t)b * N1 + p0 + (Q)) * 3;                      \
    idx3[o3]     = (I0);                                              \
    idx3[o3 + 1] = (I1);                                              \
    idx3[o3 + 2] = (I2);                                              \
    w3[o3]     = r0 * inv;                                            \
    w3[o3 + 1] = r1 * inv;                                            \
    w3[o3 + 2] = r2 * inv;                                            \
} while (0)

__global__ __launch_bounds__(256)
__attribute__((amdgpu_waves_per_eu(8, 8)))
void knn_kernel(
    const float* __restrict__ xyz1, const float4* __restrict__ xyz2q,
    int* __restrict__ idx3, float* __restrict__ w3)
{
    __shared__ float4 slds[1024];   // 16384 B

    int tid = threadIdx.x;
    int b   = blockIdx.y;
    int n0  = blockIdx.x * 32;

    int s  = tid & 15;
    int g  = tid >> 4;
    int p0 = n0 + g * 2;

    size_t pb = ((size_t)b * N1 + p0) * 3;
    float x0 = xyz1[pb + 0], y0 = xyz1[pb + 1], z0 = xyz1[pb + 2];
    float x1 = xyz1[pb + 3], y1 = xyz1[pb + 4], z1 = xyz1[pb + 5];
    float ax0 = -2.f * x0, ay0 = -2.f * y0, az0 = -2.f * z0;
    float ax1 = -2.f * x1, ay1 = -2.f * y1, az1 = -2.f * z1;
    float pp0 = fmaf(x0, x0, fmaf(y0, y0, z0 * z0));
    float pp1 = fmaf(x1, x1, fmaf(y1, y1, z1 * z1));

    float da0 = 1e30f, da1 = 1e30f, da2 = 1e30f;
    float db0 = 1e30f, db1 = 1e30f, db2 = 1e30f;
    int   ia0 = 0, ia1 = 0, ia2 = 0;
    int   ib0 = 0, ib1 = 0, ib2 = 0;

#pragma unroll
    for (int stage = 0; stage < 4; ++stage) {
        int base = stage * 1024;
#pragma unroll
        for (int i = 0; i < 4; ++i)
            slds[tid + i * 256] = xyz2q[(size_t)b * N2 + base + tid + i * 256];
        __syncthreads();

#pragma unroll 4
        for (int k = 0; k < 64; ++k) {
            int c = s + (k << 4);
            float4 v = slds[c];
            int cand = base + c;
            float t0 = fmaf(ax0, v.x, fmaf(ay0, v.y, fmaf(az0, v.z, v.w)));
            float t1 = fmaf(ax1, v.x, fmaf(ay1, v.y, fmaf(az1, v.z, v.w)));
            BINS(t0, cand, da0, da1, da2, ia0, ia1, ia2);
            BINS(t1, cand, db0, db1, db2, ib0, ib1, ib2);
        }
        __syncthreads();
    }

#pragma unroll
    for (int st = 1; st <= 8; st <<= 1) {
        MERGE_STEP(st, da0, da1, da2, ia0, ia1, ia2);
        MERGE_STEP(st, db0, db1, db2, ib0, ib1, ib2);
    }

    if (s == 0) {
        KNN_OUT(0, da0, da1, da2, ia0, ia1, ia2, pp0);
        KNN_OUT(1, db0, db1, db2, ib0, ib1, ib2, pp1);
    }
}

// =====================================================================
// Fused interpolate + concat + MLP(384->256->256, BN+ReLU) + channel max
// 64-POINT TILE, 512-thread (8-wave) blocks.
// Rationale: the 32-pt version streams the full 320 KB fp16 weights per
// block (2048 blocks -> 655 MB L2 traffic, ~80 dependent 16B loads/lane)
// -- weight-latency bound, MFMA floor is only ~3 us. 64-pt tile halves
// weight traffic and doubles MFMA per af load. Per wave: 32 out-ch
// (ot 0..1) x 64 points (pt 0..3) -> acc stays 32 VGPR;
// __launch_bounds__(512,4) holds VGPR<=128 (16 waves/CU; LDS 52.7 KB).
// Swizzle invariants unchanged: p&7 == ml&7 for all pt tiles.
// =====================================================================
__global__ __launch_bounds__(512, 4)
void mlp_kernel(
    const float* __restrict__ points1, const float* __restrict__ pointsb1,
    const float4* __restrict__ p2t4,
    const int* __restrict__ idx3, const float* __restrict__ w3,
    const uint4* __restrict__ W0v, const uint4* __restrict__ W1v,
    const float* __restrict__ sst, float* __restrict__ out)
{
    // x: 64 rows x 384 fp16, 16B-chunk swizzled by (p&7); h1 overlays (64x256)
    __shared__ __align__(16) u16 sx[64 * KIN];   // 49152 B
    __shared__ float sred[8][64];                 // 2048 B
    __shared__ int   s_idx[192];
    __shared__ float s_w[192];

    int tid = threadIdx.x;
    int b   = blockIdx.y;
    int n0  = blockIdx.x * 64;

    if (tid < 192) {
        size_t gi = ((size_t)b * N1 + n0) * 3 + tid;
        s_idx[tid] = idx3[gi];
        s_w[tid]   = w3[gi];
    }

    // ---- stage x rows 0..127 (points1) + 256..383 (points_b1) ----
    int pL  = tid & 63;              // point 0..63
    int cg4 = (tid >> 6) * 4;        // row-quad base 0,4,...,28
#pragma unroll
    for (int k = 0; k < 4; ++k) {
        int r4 = cg4 + 32 * k;       // rows 0..124 step 4
        size_t base = ((size_t)b * CC + r4) * N1 + n0 + pL;
        float a0 = points1[base];
        float a1 = points1[base + (size_t)N1];
        float a2 = points1[base + (size_t)2 * N1];
        float a3 = points1[base + (size_t)3 * N1];
        u32 lo = f2h(a0) | ((u32)f2h(a1) << 16);
        u32 hi = f2h(a2) | ((u32)f2h(a3) << 16);
        int chunk = (r4 >> 3) ^ (pL & 7);
        *(uint2*)&sx[pL * KIN + chunk * 8 + (r4 & 7)] = make_uint2(lo, hi);
    }
#pragma unroll
    for (int k = 0; k < 4; ++k) {
        int r4 = cg4 + 32 * k;
        int k4 = 256 + r4;
        size_t base = ((size_t)b * CC + r4) * N1 + n0 + pL;
        float a0 = pointsb1[base];
        float a1 = pointsb1[base + (size_t)N1];
        float a2 = pointsb1[base + (size_t)2 * N1];
        float a3 = pointsb1[base + (size_t)3 * N1];
        u32 lo = f2h(a0) | ((u32)f2h(a1) << 16);
        u32 hi = f2h(a2) | ((u32)f2h(a3) << 16);
        int chunk = (k4 >> 3) ^ (pL & 7);
        *(uint2*)&sx[pL * KIN + chunk * 8 + (k4 & 7)] = make_uint2(lo, hi);
    }
    __syncthreads();   // s_idx/s_w visible for gather

    // ---- stage x rows 128..255: 3-NN interpolation from p2t rows ----
    int c4  = tid & 31;              // channel-quad 0..31
    int pg  = tid >> 5;              // 0..15
    int k4g = 128 + c4 * 4;
#pragma unroll
    for (int k = 0; k < 4; ++k) {
        int p = pg + 16 * k;         // point 0..63
        float w0w = s_w[p * 3 + 0], w1w = s_w[p * 3 + 1], w2w = s_w[p * 3 + 2];
        float4 f0 = p2t4[((size_t)b * N2 + s_idx[p * 3 + 0]) * 32 + c4];
        float4 f1 = p2t4[((size_t)b * N2 + s_idx[p * 3 + 1]) * 32 + c4];
        float4 f2 = p2t4[((size_t)b * N2 + s_idx[p * 3 + 2]) * 32 + c4];
        float e0 = fmaf(w0w, f0.x, fmaf(w1w, f1.x, w2w * f2.x));
        float e1 = fmaf(w0w, f0.y, fmaf(w1w, f1.y, w2w * f2.y));
        float e2 = fmaf(w0w, f0.z, fmaf(w1w, f1.z, w2w * f2.z));
        float e3 = fmaf(w0w, f0.w, fmaf(w1w, f1.w, w2w * f2.w));
        u32 lo = f2h(e0) | ((u32)f2h(e1) << 16);
        u32 hi = f2h(e2) | ((u32)f2h(e3) << 16);
        int chunk = (k4g >> 3) ^ (p & 7);
        *(uint2*)&sx[p * KIN + chunk * 8 + (k4g & 7)] = make_uint2(lo, hi);
    }
    __syncthreads();

    int lane = tid & 63, w = tid >> 6;      // wave w in 0..7: o in [w*32, w*32+32)
    int ml = lane & 15, ql = lane >> 4;     // frag row/col, quad
    int px7 = ml & 7;                       // == p&7 for all pt (p=pt*16+ml)

    // ---------------- GEMM1: h1 = W0 @ x ----------------
    v4f acc1[2][4];
#pragma unroll
    for (int ot = 0; ot < 2; ++ot)
        for (int pt = 0; pt < 4; ++pt)
            acc1[ot][pt] = (v4f){0.f, 0.f, 0.f, 0.f};

#pragma unroll
    for (int s = 0; s < 12; ++s) {
        int kc = s * 4 + ql;
        int pc = (kc ^ px7) * 8;
        v8h bf0 = __builtin_bit_cast(v8h, *(const uint4*)&sx[ml * KIN + pc]);
        v8h bf1 = __builtin_bit_cast(v8h, *(const uint4*)&sx[(16 + ml) * KIN + pc]);
        v8h bf2 = __builtin_bit_cast(v8h, *(const uint4*)&sx[(32 + ml) * KIN + pc]);
        v8h bf3 = __builtin_bit_cast(v8h, *(const uint4*)&sx[(48 + ml) * KIN + pc]);
#pragma unroll
        for (int ot = 0; ot < 2; ++ot) {
            int o = w * 32 + ot * 16 + ml;
            v8h af = __builtin_bit_cast(v8h, W0v[o * 48 + kc]);
            acc1[ot][0] = __builtin_amdgcn_mfma_f32_16x16x32_f16(af, bf0, acc1[ot][0], 0, 0, 0);
            acc1[ot][1] = __builtin_amdgcn_mfma_f32_16x16x32_f16(af, bf1, acc1[ot][1], 0, 0, 0);
            acc1[ot][2] = __builtin_amdgcn_mfma_f32_16x16x32_f16(af, bf2, acc1[ot][2], 0, 0, 0);
            acc1[ot][3] = __builtin_amdgcn_mfma_f32_16x16x32_f16(af, bf3, acc1[ot][3], 0, 0, 0);
        }
    }
    __syncthreads();   // all x reads done before h1 overlays sx

    // epilogue 1: BN+ReLU -> fp16 h1[p][o] (row stride 256, swizzled)
    const float* s0v = sst;
    const float* t0v = sst + 256;
#pragma unroll
    for (int ot = 0; ot < 2; ++ot) {
        int o0 = w * 32 + ot * 16 + ql * 4;
        float sc0 = s0v[o0], sc1 = s0v[o0 + 1], sc2 = s0v[o0 + 2], sc3 = s0v[o0 + 3];
        float sh0 = t0v[o0], sh1 = t0v[o0 + 1], sh2 = t0v[o0 + 2], sh3 = t0v[o0 + 3];
        int chunk = ((o0 >> 3) ^ px7);
#pragma unroll
        for (int pt = 0; pt < 4; ++pt) {
            int p = pt * 16 + ml;
            float z0 = fmaxf(fmaf(acc1[ot][pt][0], sc0, sh0), 0.f);
            float z1 = fmaxf(fmaf(acc1[ot][pt][1], sc1, sh1), 0.f);
            float z2 = fmaxf(fmaf(acc1[ot][pt][2], sc2, sh2), 0.f);
            float z3 = fmaxf(fmaf(acc1[ot][pt][3], sc3, sh3), 0.f);
            u32 lo = f2h(z0) | ((u32)f2h(z1) << 16);
            u32 hi = f2h(z2) | ((u32)f2h(z3) << 16);
            *(uint2*)&sx[p * HID + chunk * 8 + (o0 & 7)] = make_uint2(lo, hi);
        }
    }
    __syncthreads();

    // ---------------- GEMM2: h2 = W1 @ h1 ----------------
    v4f acc2[2][4];
#pragma unroll
    for (int ot = 0; ot < 2; ++ot)
        for (int pt = 0; pt < 4; ++pt)
            acc2[ot][pt] = (v4f){0.f, 0.f, 0.f, 0.f};

#pragma unroll
    for (int s = 0; s < 8; ++s) {
        int kc = s * 4 + ql;
        int pc = (kc ^ px7) * 8;
        v8h bf0 = __builtin_bit_cast(v8h, *(const uint4*)&sx[ml * HID + pc]);
        v8h bf1 = __builtin_bit_cast(v8h, *(const uint4*)&sx[(16 + ml) * HID + pc]);
        v8h bf2 = __builtin_bit_cast(v8h, *(const uint4*)&sx[(32 + ml) * HID + pc]);
        v8h bf3 = __builtin_bit_cast(v8h, *(const uint4*)&sx[(48 + ml) * HID + pc]);
#pragma unroll
        for (int ot = 0; ot < 2; ++ot) {
            int o = w * 32 + ot * 16 + ml;
            v8h af = __builtin_bit_cast(v8h, W1v[o * 32 + kc]);
            acc2[ot][0] = __builtin_amdgcn_mfma_f32_16x16x32_f16(af, bf0, acc2[ot][0], 0, 0, 0);
            acc2[ot][1] = __builtin_amdgcn_mfma_f32_16x16x32_f16(af, bf1, acc2[ot][1], 0, 0, 0);
            acc2[ot][2] = __builtin_amdgcn_mfma_f32_16x16x32_f16(af, bf2, acc2[ot][2], 0, 0, 0);
            acc2[ot][3] = __builtin_amdgcn_mfma_f32_16x16x32_f16(af, bf3, acc2[ot][3], 0, 0, 0);
        }
    }

    // epilogue 2: BN + ReLU (via max with 0) + channel max over this wave's 32 o
    const float* s1v = sst + 512;
    const float* t1v = sst + 768;
    float mx0 = 0.f, mx1 = 0.f, mx2 = 0.f, mx3 = 0.f;   // relu floor = 0
#pragma unroll
    for (int ot = 0; ot < 2; ++ot) {
        int o0 = w * 32 + ot * 16 + ql * 4;
#pragma unroll
        for (int r = 0; r < 4; ++r) {
            float sc = s1v[o0 + r], sh = t1v[o0 + r];
            mx0 = fmaxf(mx0, fmaf(acc2[ot][0][r], sc, sh));
            mx1 = fmaxf(mx1, fmaf(acc2[ot][1][r], sc, sh));
            mx2 = fmaxf(mx2, fmaf(acc2[ot][2][r], sc, sh));
            mx3 = fmaxf(mx3, fmaf(acc2[ot][3][r], sc, sh));
        }
    }
    mx0 = fmaxf(mx0, __shfl_xor(mx0, 16, 64));
    mx0 = fmaxf(mx0, __shfl_xor(mx0, 32, 64));
    mx1 = fmaxf(mx1, __shfl_xor(mx1, 16, 64));
    mx1 = fmaxf(mx1, __shfl_xor(mx1, 32, 64));
    mx2 = fmaxf(mx2, __shfl_xor(mx2, 16, 64));
    mx2 = fmaxf(mx2, __shfl_xor(mx2, 32, 64));
    mx3 = fmaxf(mx3, __shfl_xor(mx3, 16, 64));
    mx3 = fmaxf(mx3, __shfl_xor(mx3, 32, 64));
    if (lane < 16) {
        sred[w][ml]      = mx0;
        sred[w][16 + ml] = mx1;
        sred[w][32 + ml] = mx2;
        sred[w][48 + ml] = mx3;
    }
    __syncthreads();
    if (tid < 64) {
        float m = sred[0][tid];
#pragma unroll
        for (int wv = 1; wv < 8; ++wv)
            m = fmaxf(m, sred[wv][tid]);
        out[(size_t)b * N1 + n0 + tid] = m;
    }
}

// =====================================================================
extern "C" void kernel_launch(void* const* d_in, const int* in_sizes, int n_in,
                              void* d_out, int out_size, void* d_ws, size_t ws_size,
                              hipStream_t stream)
{
    const float* xyz1     = (const float*)d_in[0];
    const float* xyz2     = (const float*)d_in[1];
    const float* points2  = (const float*)d_in[2];
    const float* points1  = (const float*)d_in[3];
    const float* pointsb1 = (const float*)d_in[4];
    const float* w0   = (const float*)d_in[5];
    const float* b0   = (const float*)d_in[6];
    const float* g0   = (const float*)d_in[7];
    const float* be0  = (const float*)d_in[8];
    const float* m0   = (const float*)d_in[9];
    const float* v0   = (const float*)d_in[10];
    const float* w1   = (const float*)d_in[11];
    const float* b1   = (const float*)d_in[12];
    const float* g1   = (const float*)d_in[13];
    const float* be1  = (const float*)d_in[14];
    const float* m1   = (const float*)d_in[15];
    const float* v1   = (const float*)d_in[16];
    float* out = (float*)d_out;

    char* ws = (char*)d_ws;
    u16*    W0h   = (u16*)(ws + 0);
    u16*    W1h   = (u16*)(ws + 196608);
    float*  sst   = (float*)(ws + 327680);
    float4* xyz2q = (float4*)(ws + 331776);
    int*    idx3  = (int*)(ws + 593920);
    float*  w3    = (float*)(ws + 1380352);
    float*  p2t   = (float*)(ws + 2166784);

    prep_transpose_kernel<<<962, 256, 0, stream>>>(
        w0, w1, b0, g0, be0, m0, v0,
        b1, g1, be1, m1, v1,
        xyz2, points2,
        W0h, W1h, sst, xyz2q, p2t);
    knn_kernel<<<dim3(512, 4), 256, 0, stream>>>(xyz1, xyz2q, idx3, w3);
    mlp_kernel<<<dim3(256, 4), 512, 0, stream>>>(points1, pointsb1,
                                                 (const float4*)p2t, idx3, w3,
                                                 (const uint4*)W0h, (const uint4*)W1h,
                                                 sst, out);
}